// Round 7
// baseline (1348.157 us; speedup 1.0000x reference)
//
#include <hip/hip_runtime.h>
#include <hip/hip_bf16.h>

typedef __bf16 bf16;
typedef __attribute__((ext_vector_type(4))) __bf16 bf16x4;
typedef __attribute__((ext_vector_type(8))) __bf16 bf16x8;
typedef __attribute__((ext_vector_type(4))) float f32x4;

// ---------------- async global->LDS helper (16B per lane, wave-uniform LDS base) ----
__device__ __forceinline__ void async_ld16(const void* g, void* l) {
    __builtin_amdgcn_global_load_lds(
        (const __attribute__((address_space(1))) unsigned int*)g,
        (__attribute__((address_space(3))) unsigned int*)l, 16, 0, 0);
}

// ------- fp32 -> bf16 transposed weight convert: in[K][N] -> out[N][K], 2 layers ----
__global__ __launch_bounds__(256) void k_f2bt(const float* __restrict__ in,
                                              bf16* __restrict__ out, int Kd, int Nd) {
    size_t loff = (size_t)blockIdx.y * Kd * Nd;
    int id = blockIdx.x * 256 + threadIdx.x;
    if (id >= Kd * Nd) return;
    int k = id / Nd, n = id - k * Nd;
    out[loff + (size_t)n * Kd + k] = (bf16)in[loff + id];
}

// ------- one-shot attention setup: relIdx table + head-major rpb transpose ---------
__global__ __launch_bounds__(256) void k_aux(const float* __restrict__ rpb,
                                             unsigned short* __restrict__ ridx,
                                             float* __restrict__ rpbT) {
    int e = blockIdx.x * 256 + threadIdx.x;
    if (e < 2401) {
        int i = e / 49, j = e - i * 49;
        int yi = i / 7, xi = i - yi * 7, yj = j / 7, xj = j - yj * 7;
        ridx[e] = (unsigned short)((yi - yj + 6) * 13 + (xi - xj + 6));
    }
    if (e < 4056) {   // 2 layers x 12 heads x 169
        int l = e / 2028, r = e - l * 2028;
        int h = r / 169, p = r - h * 169;
        rpbT[e] = rpb[l * 2028 + p * 12 + h];
    }
}

// ---------------- fused reorder_in + LayerNorm1(l=0): one wave per token -----------
__global__ __launch_bounds__(256) void k_lnr(const float* __restrict__ x,
                                             const float* __restrict__ s,
                                             const float* __restrict__ b,
                                             float* __restrict__ xres,
                                             bf16* __restrict__ h) {
    int traw = blockIdx.x * 4 + (threadIdx.x >> 6);
    int lane = threadIdx.x & 63;
    int bb = traw / 3136;
    int rem = traw - bb * 3136;
    int y = rem / 56, xc = rem - y * 56;
    int w = bb * 64 + (y / 7) * 8 + (xc / 7);
    int n = (y % 7) * 7 + (xc % 7);
    int twin = w * 49 + n;

    const float4* row = (const float4*)(x + (size_t)traw * 384);  // 96 float4
    float4 v0 = row[lane];
    float4 v1 = make_float4(0.f, 0.f, 0.f, 0.f);
    if (lane < 32) v1 = row[64 + lane];
    float sum = v0.x + v0.y + v0.z + v0.w + v1.x + v1.y + v1.z + v1.w;
#pragma unroll
    for (int m = 1; m < 64; m <<= 1) sum += __shfl_xor(sum, m);
    float mu = sum * (1.f / 384.f);
    float sq = (v0.x - mu) * (v0.x - mu) + (v0.y - mu) * (v0.y - mu) +
               (v0.z - mu) * (v0.z - mu) + (v0.w - mu) * (v0.w - mu);
    if (lane < 32)
        sq += (v1.x - mu) * (v1.x - mu) + (v1.y - mu) * (v1.y - mu) +
              (v1.z - mu) * (v1.z - mu) + (v1.w - mu) * (v1.w - mu);
#pragma unroll
    for (int m = 1; m < 64; m <<= 1) sq += __shfl_xor(sq, m);
    float r = rsqrtf(sq * (1.f / 384.f) + 1e-6f);

    float4* xr = (float4*)(xres + (size_t)twin * 384);
    const float4* s4 = (const float4*)s;
    const float4* b4 = (const float4*)b;
    bf16* ho = h + (size_t)twin * 384;
    {
        xr[lane] = v0;
        float4 sv = s4[lane], bv = b4[lane];
        bf16x4 ov;
        ov[0] = (bf16)((v0.x - mu) * r * sv.x + bv.x);
        ov[1] = (bf16)((v0.y - mu) * r * sv.y + bv.y);
        ov[2] = (bf16)((v0.z - mu) * r * sv.z + bv.z);
        ov[3] = (bf16)((v0.w - mu) * r * sv.w + bv.w);
        *(bf16x4*)&ho[lane * 4] = ov;
    }
    if (lane < 32) {
        xr[64 + lane] = v1;
        float4 sv = s4[64 + lane], bv = b4[64 + lane];
        bf16x4 ov;
        ov[0] = (bf16)((v1.x - mu) * r * sv.x + bv.x);
        ov[1] = (bf16)((v1.y - mu) * r * sv.y + bv.y);
        ov[2] = (bf16)((v1.z - mu) * r * sv.z + bv.z);
        ov[3] = (bf16)((v1.w - mu) * r * sv.w + bv.w);
        *(bf16x4*)&ho[256 + lane * 4] = ov;
    }
}

// ---------------- LayerNorm: fp32 residual -> bf16 ---------------------------------
__global__ __launch_bounds__(256) void k_ln(const float* __restrict__ xres,
                                            const float* __restrict__ s,
                                            const float* __restrict__ b,
                                            bf16* __restrict__ h) {
    int t = blockIdx.x * 4 + (threadIdx.x >> 6);
    int lane = threadIdx.x & 63;
    const float4* row = (const float4*)(xres + (size_t)t * 384);
    float4 v0 = row[lane];
    float4 v1 = make_float4(0.f, 0.f, 0.f, 0.f);
    if (lane < 32) v1 = row[64 + lane];
    float sum = v0.x + v0.y + v0.z + v0.w + v1.x + v1.y + v1.z + v1.w;
#pragma unroll
    for (int m = 1; m < 64; m <<= 1) sum += __shfl_xor(sum, m);
    float mu = sum * (1.f / 384.f);
    float sq = (v0.x - mu) * (v0.x - mu) + (v0.y - mu) * (v0.y - mu) +
               (v0.z - mu) * (v0.z - mu) + (v0.w - mu) * (v0.w - mu);
    if (lane < 32)
        sq += (v1.x - mu) * (v1.x - mu) + (v1.y - mu) * (v1.y - mu) +
              (v1.z - mu) * (v1.z - mu) + (v1.w - mu) * (v1.w - mu);
#pragma unroll
    for (int m = 1; m < 64; m <<= 1) sq += __shfl_xor(sq, m);
    float r = rsqrtf(sq * (1.f / 384.f) + 1e-6f);
    const float4* s4 = (const float4*)s;
    const float4* b4 = (const float4*)b;
    bf16* ho = h + (size_t)t * 384;
    {
        float4 sv = s4[lane], bv = b4[lane];
        bf16x4 ov;
        ov[0] = (bf16)((v0.x - mu) * r * sv.x + bv.x);
        ov[1] = (bf16)((v0.y - mu) * r * sv.y + bv.y);
        ov[2] = (bf16)((v0.z - mu) * r * sv.z + bv.z);
        ov[3] = (bf16)((v0.w - mu) * r * sv.w + bv.w);
        *(bf16x4*)&ho[lane * 4] = ov;
    }
    if (lane < 32) {
        float4 sv = s4[64 + lane], bv = b4[64 + lane];
        bf16x4 ov;
        ov[0] = (bf16)((v1.x - mu) * r * sv.x + bv.x);
        ov[1] = (bf16)((v1.y - mu) * r * sv.y + bv.y);
        ov[2] = (bf16)((v1.z - mu) * r * sv.z + bv.z);
        ov[3] = (bf16)((v1.w - mu) * r * sv.w + bv.w);
        *(bf16x4*)&ho[256 + lane * 4] = ov;
    }
}

// ---------------- GELU (tanh approximation, matches jax.nn.gelu) -------------------
__device__ inline float gelu_f(float x) {
    float u = 0.7978845608028654f * (x + 0.044715f * x * x * x);
    float t = 1.f - 2.f / (__expf(2.f * u) + 1.f);
    return 0.5f * x * (1.f + t);
}

// ---------------- GEMM: C[M,N] = A[M,K] @ Bt[N,K]^T (+epilogue) --------------------
// EPI 0: store bf16 | 1: +bias, gelu, store bf16 | 2: resid += | 3: resid += val+bias
// EPI 4: outf[perm(row)] = resid + val + bias (fp32, fused reorder_out)
// 128x128 tile, BK=32, 4 waves (2x2). A: global_load_lds into 3 LDS buffers (24KB),
// depth-2, kseg XOR swizzle (R5-verified path). B: DIRECT FROM L2 into VGPRs —
// weights are <=1.2MB, fully L2-resident (FETCH=23.6MB proved it), so B skips LDS.
// This halves LDS-read traffic per K-step (the measured binding resource: 96KB/CU
// ~= 1150cy ~= period) and cuts LDS footprint 49->24KB -> 4 blocks/CU at
// launch_bounds(256,4) (more TLP, unlike the R4/R6 big-tile attempts).
// B prefetched 1 iter ahead (bnxt, static indexing). Boundary: one barrier/K-step;
// vmcnt(6) steady [A(t+1)=2 + B(t)=4 may remain], vmcnt(4) at last iter.
template <int EPI>
__global__ __launch_bounds__(256, 4) void k_gemm(const bf16* __restrict__ A,
                                                 const bf16* __restrict__ Bt,
                                                 const float* __restrict__ bias,
                                                 float* __restrict__ resid,
                                                 bf16* __restrict__ Cout,
                                                 float* __restrict__ outf,
                                                 int N, int K) {
    __shared__ __align__(16) char lds[24576];   // 3 x A 8KB; epilogue scratch reuses
    int tid = threadIdx.x;

    // XCD-aware chunked remap (bijective, m204)
    int nwg = gridDim.x * gridDim.y;
    int orig = blockIdx.y * gridDim.x + blockIdx.x;
    int q = nwg >> 3, r8 = nwg & 7;
    int xcd = orig & 7, idx = orig >> 3;
    int wg = (xcd < r8 ? xcd * (q + 1) : r8 * (q + 1) + (xcd - r8) * q) + idx;
    int n0 = (wg % gridDim.x) * 128;
    int m0 = (wg / gridDim.x) * 128;

    int wave = tid >> 6, lane = tid & 63;
    int wm = (wave >> 1) * 64, wn = (wave & 1) * 64;
    int col = lane & 15, quad = lane >> 4;

    f32x4 acc[4][4] = {};

    int r0 = 2 * wave * 16 + (lane >> 2);
    int ksl = (lane & 3) ^ ((r0 >> 1) & 3);
    const bf16* ga0 = A + (size_t)(m0 + r0) * K + ksl * 8;
    size_t rowK16 = (size_t)16 * K;
    int ldsoff = 2 * wave * 512;   // per-wave A staging base (bf16 elems)

    // per-lane B base: row n0+wn+col, k-chunk quad*8 (same fragment the LDS round
    // trip produced in R5; no swizzle needed without LDS)
    const bf16* gB = Bt + (size_t)(n0 + wn + col) * K + quad * 8;
    size_t fr16 = (size_t)16 * K;   // fragment row stride (16 rows)

    int NT = K >> 5;

    auto stageA = [&](int t, int b) {
        const bf16* a = ga0 + t * 32;
        bf16* Ab = (bf16*)(lds + b * 8192);
        async_ld16(a, Ab + ldsoff);
        async_ld16(a + rowK16, Ab + ldsoff + 512);
    };

    // prologue: 2 A-tiles in flight; B(0) into registers
    stageA(0, 0);
    stageA(1, 1);
    bf16x8 bcur[4], bnxt[4];
#pragma unroll
    for (int i = 0; i < 4; i++) bcur[i] = *(const bf16x8*)(gB + i * fr16);

    int buf = 0;   // t % 3
    for (int t = 0; t < NT; ++t) {
        // boundary: A(t) landed (counted — A(t+1), B(t) may remain in flight);
        // previous ds_reads drained (free, enables refill of buf freed at t-1).
        if (t < NT - 1)
            asm volatile("s_waitcnt vmcnt(6) lgkmcnt(0)\n\ts_barrier" ::: "memory");
        else
            asm volatile("s_waitcnt vmcnt(4) lgkmcnt(0)\n\ts_barrier" ::: "memory");

        if (t + 2 < NT) {                    // refill A buffer freed at t-1
            int sb = buf + 2; if (sb >= 3) sb -= 3;
            stageA(t + 2, sb);
        }
        if (t + 1 < NT) {                    // prefetch next B fragments into regs
            const bf16* gb = gB + (t + 1) * 32;
#pragma unroll
            for (int i = 0; i < 4; i++) bnxt[i] = *(const bf16x8*)(gb + i * fr16);
        }

        const bf16* Ab = (const bf16*)(lds + buf * 8192);
        bf16x8 af[4];
#pragma unroll
        for (int i = 0; i < 4; i++) {
            int ra = wm + i * 16 + col;
            af[i] = *(const bf16x8*)&Ab[ra * 32 + ((quad ^ ((ra >> 1) & 3)) << 3)];
        }
#pragma unroll
        for (int mi = 0; mi < 4; mi++)
#pragma unroll
            for (int ni = 0; ni < 4; ni++)
                acc[mi][ni] = __builtin_amdgcn_mfma_f32_16x16x32_bf16(
                    af[mi], bcur[ni], acc[mi][ni], 0, 0, 0);
#pragma unroll
        for (int i = 0; i < 4; i++) bcur[i] = bnxt[i];
        buf = (buf == 2) ? 0 : buf + 1;
    }

    __syncthreads();   // LDS becomes epilogue scratch
    float* scrw = (float*)lds + wave * (16 * 68) / 4 * 4;   // wave*1088 floats
    scrw = (float*)lds + wave * (16 * 68);

    int prow = lane >> 3;
    int pc0 = (lane & 7) * 8;
#pragma unroll
    for (int mi = 0; mi < 4; mi++) {
#pragma unroll
        for (int ni = 0; ni < 4; ni++)
#pragma unroll
            for (int r = 0; r < 4; r++)
                scrw[(quad * 4 + r) * 68 + ni * 16 + col] = acc[mi][ni][r];
#pragma unroll
        for (int h = 0; h < 2; h++) {
            int lr = h * 8 + prow;
            const float* sp = scrw + lr * 68 + pc0;
            float4 u0 = *(const float4*)sp;
            float4 u1 = *(const float4*)(sp + 4);
            int gm = m0 + wm + mi * 16 + lr;
            int gn = n0 + wn + pc0;
            size_t off = (size_t)gm * N + gn;
            if (EPI == 0) {
                bf16x8 ov;
                ov[0] = (bf16)u0.x; ov[1] = (bf16)u0.y; ov[2] = (bf16)u0.z; ov[3] = (bf16)u0.w;
                ov[4] = (bf16)u1.x; ov[5] = (bf16)u1.y; ov[6] = (bf16)u1.z; ov[7] = (bf16)u1.w;
                *(bf16x8*)&Cout[off] = ov;
            } else if (EPI == 1) {
                float4 b0 = *(const float4*)&bias[gn];
                float4 b1 = *(const float4*)&bias[gn + 4];
                bf16x8 ov;
                ov[0] = (bf16)gelu_f(u0.x + b0.x); ov[1] = (bf16)gelu_f(u0.y + b0.y);
                ov[2] = (bf16)gelu_f(u0.z + b0.z); ov[3] = (bf16)gelu_f(u0.w + b0.w);
                ov[4] = (bf16)gelu_f(u1.x + b1.x); ov[5] = (bf16)gelu_f(u1.y + b1.y);
                ov[6] = (bf16)gelu_f(u1.z + b1.z); ov[7] = (bf16)gelu_f(u1.w + b1.w);
                *(bf16x8*)&Cout[off] = ov;
            } else if (EPI == 2) {
                float4 r0v = *(const float4*)&resid[off];
                float4 r1v = *(const float4*)&resid[off + 4];
                r0v.x += u0.x; r0v.y += u0.y; r0v.z += u0.z; r0v.w += u0.w;
                r1v.x += u1.x; r1v.y += u1.y; r1v.z += u1.z; r1v.w += u1.w;
                *(float4*)&resid[off] = r0v;
                *(float4*)&resid[off + 4] = r1v;
            } else if (EPI == 3) {
                float4 b0 = *(const float4*)&bias[gn];
                float4 b1 = *(const float4*)&bias[gn + 4];
                float4 r0v = *(const float4*)&resid[off];
                float4 r1v = *(const float4*)&resid[off + 4];
                r0v.x += u0.x + b0.x; r0v.y += u0.y + b0.y;
                r0v.z += u0.z + b0.z; r0v.w += u0.w + b0.w;
                r1v.x += u1.x + b1.x; r1v.y += u1.y + b1.y;
                r1v.z += u1.z + b1.z; r1v.w += u1.w + b1.w;
                *(float4*)&resid[off] = r0v;
                *(float4*)&resid[off + 4] = r1v;
            } else {
                // EPI 4: fp32 out at permuted raw row (fused reorder_out)
                float4 b0 = *(const float4*)&bias[gn];
                float4 b1 = *(const float4*)&bias[gn + 4];
                float4 r0v = *(const float4*)&resid[off];
                float4 r1v = *(const float4*)&resid[off + 4];
                r0v.x += u0.x + b0.x; r0v.y += u0.y + b0.y;
                r0v.z += u0.z + b0.z; r0v.w += u0.w + b0.w;
                r1v.x += u1.x + b1.x; r1v.y += u1.y + b1.y;
                r1v.z += u1.z + b1.z; r1v.w += u1.w + b1.w;
                int wdx = gm / 49, n = gm - wdx * 49;
                int bb = wdx >> 6, r64 = wdx & 63;
                int n7 = n / 7;
                int yy = (r64 >> 3) * 7 + n7;
                int xx = (r64 & 7) * 7 + (n - n7 * 7);
                size_t traw = ((size_t)((bb * 56 + yy) * 56 + xx)) * 384 + gn;
                *(float4*)&outf[traw] = r0v;
                *(float4*)&outf[traw + 4] = r1v;
            }
        }
    }
}

// ---------------- MFMA window attention: one WAVE per (window, head) ---------------
__global__ __launch_bounds__(256) void k_attn(const bf16* __restrict__ qkv,
                                              const unsigned short* __restrict__ ridx,
                                              const float* __restrict__ rpbT,
                                              bf16* __restrict__ o) {
    __shared__ unsigned short relIdx[2401];
    __shared__ float rpbs[4][169];
    __shared__ __align__(16) bf16 Vs[4][32 * 72];
    __shared__ __align__(16) bf16 Ps[4][64 * 72];

    int tid = threadIdx.x;
    int wave = tid >> 6, lane = tid & 63;
    int col = lane & 15, quad = lane >> 4;
    int w = blockIdx.x;
    int head = blockIdx.y * 4 + wave;
    const float scale = 0.17677669529663687f;

    for (int e = tid; e < 2401; e += 256) relIdx[e] = ridx[e];
    for (int e = lane; e < 169; e += 64) rpbs[wave][e] = rpbT[head * 169 + e];

    const bf16* base = qkv + (size_t)w * 49 * 1152 + head * 32;
    bf16* vsw = Vs[wave];
    bf16* psw = Ps[wave];

    bf16x4 z4 = {(bf16)0.f, (bf16)0.f, (bf16)0.f, (bf16)0.f};
    for (int e = lane; e < 576; e += 64) *(bf16x4*)&vsw[e * 4] = z4;
    for (int e = lane; e < 392; e += 64) {
        int j = e >> 3, d4 = (e & 7) * 4;
        bf16x4 vv = *(const bf16x4*)&base[768 + (size_t)j * 1152 + d4];
        vsw[(d4 + 0) * 72 + j] = vv[0];
        vsw[(d4 + 1) * 72 + j] = vv[1];
        vsw[(d4 + 2) * 72 + j] = vv[2];
        vsw[(d4 + 3) * 72 + j] = vv[3];
    }

    __syncthreads();

    bf16x8 qf[4], kf[4];
#pragma unroll
    for (int mi = 0; mi < 4; mi++) {
        size_t row = (size_t)(mi * 16 + col) * 1152 + quad * 8;
        qf[mi] = *(const bf16x8*)&base[row];
        kf[mi] = *(const bf16x8*)&base[384 + row];
    }

    f32x4 S[4][4] = {};
#pragma unroll
    for (int mi = 0; mi < 4; mi++)
#pragma unroll
        for (int nj = 0; nj < 4; nj++)
            S[mi][nj] = __builtin_amdgcn_mfma_f32_16x16x32_bf16(qf[mi], kf[nj], S[mi][nj], 0, 0, 0);

    float* rp = rpbs[wave];
#pragma unroll
    for (int mi = 0; mi < 4; mi++) {
#pragma unroll
        for (int r = 0; r < 4; r++) {
            int ii = mi * 16 + quad * 4 + r;
            int ir = (ii < 49 ? ii : 0) * 49;
            float sv[4];
            float mx = -1e30f;
#pragma unroll
            for (int nj = 0; nj < 4; nj++) {
                int j = nj * 16 + col;
                float v;
                if (j < 49) v = S[mi][nj][r] * scale + rp[relIdx[ir + j]];
                else v = -1e30f;
                sv[nj] = v;
                mx = fmaxf(mx, v);
            }
#pragma unroll
            for (int m = 1; m < 16; m <<= 1) mx = fmaxf(mx, __shfl_xor(mx, m));
            float sum = 0.f;
#pragma unroll
            for (int nj = 0; nj < 4; nj++) {
                float p = __expf(sv[nj] - mx);
                sv[nj] = p;
                sum += p;
            }
#pragma unroll
            for (int m = 1; m < 16; m <<= 1) sum += __shfl_xor(sum, m);
            float is = 1.f / sum;
#pragma unroll
            for (int nj = 0; nj < 4; nj++)
                psw[ii * 72 + nj * 16 + col] = (bf16)(sv[nj] * is);
        }
    }

    __syncthreads();

    f32x4 O[4][2] = {};
#pragma unroll
    for (int kt = 0; kt < 2; kt++) {
        bf16x8 vb[2];
#pragma unroll
        for (int nt = 0; nt < 2; nt++)
            vb[nt] = *(const bf16x8*)&vsw[(nt * 16 + col) * 72 + kt * 32 + quad * 8];
#pragma unroll
        for (int mi = 0; mi < 4; mi++) {
            bf16x8 pa = *(const bf16x8*)&psw[(mi * 16 + col) * 72 + kt * 32 + quad * 8];
#pragma unroll
            for (int nt = 0; nt < 2; nt++)
                O[mi][nt] = __builtin_amdgcn_mfma_f32_16x16x32_bf16(pa, vb[nt], O[mi][nt], 0, 0, 0);
        }
    }

    bf16* ob = o + (size_t)w * 49 * 384 + head * 32;
#pragma unroll
    for (int mi = 0; mi < 4; mi++) {
#pragma unroll
        for (int r = 0; r < 4; r++) {
            int i = mi * 16 + quad * 4 + r;
            if (i < 49) {
#pragma unroll
                for (int nt = 0; nt < 2; nt++)
                    ob[(size_t)i * 384 + nt * 16 + col] = (bf16)O[mi][nt][r];
            }
        }
    }
}

// ---------------- launch ----------------
extern "C" void kernel_launch(void* const* d_in, const int* in_sizes, int n_in,
                              void* d_out, int out_size, void* d_ws, size_t ws_size,
                              hipStream_t stream) {
    const float* x      = (const float*)d_in[0];
    const float* ln1_s  = (const float*)d_in[1];
    const float* ln1_b  = (const float*)d_in[2];
    const float* qkv_w  = (const float*)d_in[3];
    const float* rpb    = (const float*)d_in[4];
    const float* proj_w = (const float*)d_in[5];
    const float* ln2_s  = (const float*)d_in[6];
    const float* ln2_b  = (const float*)d_in[7];
    const float* mlp_w1 = (const float*)d_in[8];
    const float* mlp_b1 = (const float*)d_in[9];
    const float* mlp_w2 = (const float*)d_in[10];
    const float* mlp_b2 = (const float*)d_in[11];
    float* out = (float*)d_out;

    char* ws = (char*)d_ws;
    float* xres  = (float*)ws;                     // 77,070,336 B
    bf16* qkvbuf = (bf16*)(ws + 77070336);         // 115,605,504 B
    bf16* obuf   = (bf16*)(ws + 192675840);        // 38,535,168 B
    bf16* wbuf   = (bf16*)(ws + 231211008);        // 7,077,888 B
    bf16* hidden = qkvbuf;                         // aliases qkv+obuf (154,140,672 B)
    bf16* hbuf   = (bf16*)d_out;                   // 38.5 MB scratch inside 77 MB out

    unsigned short* ridx = (unsigned short*)((char*)d_out + 40000000);   // 4,802 B
    float* rpbT          = (float*)((char*)d_out + 40016384);            // 16,224 B

    bf16* qkvw_b  = wbuf;                 // 884,736 elems (2 layers, transposed [N][K])
    bf16* projw_b = wbuf + 884736;        // 294,912
    bf16* mlp1_b  = wbuf + 1179648;       // 1,179,648
    bf16* mlp2_b  = wbuf + 2359296;       // 1,179,648

    k_f2bt<<<dim3(1728, 2), 256, 0, stream>>>(qkv_w, qkvw_b, 384, 1152);
    k_f2bt<<<dim3(576, 2), 256, 0, stream>>>(proj_w, projw_b, 384, 384);
    k_f2bt<<<dim3(2304, 2), 256, 0, stream>>>(mlp_w1, mlp1_b, 384, 1536);
    k_f2bt<<<dim3(2304, 2), 256, 0, stream>>>(mlp_w2, mlp2_b, 1536, 384);
    k_aux<<<16, 256, 0, stream>>>(rpb, ridx, rpbT);

    // fused reorder_in + LN1(l=0)
    k_lnr<<<12544, 256, 0, stream>>>(x, ln1_s, ln1_b, xres, hbuf);

    for (int l = 0; l < 2; l++) {
        k_gemm<0><<<dim3(9, 392), 256, 0, stream>>>(
            hbuf, qkvw_b + (size_t)l * 442368, nullptr, nullptr, qkvbuf, nullptr, 1152, 384);
        k_attn<<<dim3(1024, 3), 256, 0, stream>>>(qkvbuf, ridx, rpbT + l * 2028, obuf);
        k_gemm<2><<<dim3(3, 392), 256, 0, stream>>>(
            obuf, projw_b + (size_t)l * 147456, nullptr, xres, nullptr, nullptr, 384, 384);
        k_ln<<<12544, 256, 0, stream>>>(xres, ln2_s + l * 384, ln2_b + l * 384, hbuf);
        k_gemm<1><<<dim3(12, 392), 256, 0, stream>>>(
            hbuf, mlp1_b + (size_t)l * 589824, mlp_b1 + l * 1536, nullptr, hidden, nullptr, 1536, 384);
        if (l == 0) {
            k_gemm<3><<<dim3(3, 392), 256, 0, stream>>>(
                hidden, mlp2_b, mlp_b2, xres, nullptr, nullptr, 384, 1536);
            k_ln<<<12544, 256, 0, stream>>>(xres, ln1_s + 384, ln1_b + 384, hbuf);
        } else {
            k_gemm<4><<<dim3(3, 392), 256, 0, stream>>>(
                hidden, mlp2_b + 589824, mlp_b2 + 384, xres, nullptr, out, 384, 1536);
        }
    }
}

// Round 8
// 1060.069 us; speedup vs baseline: 1.2718x; 1.2718x over previous
//
#include <hip/hip_runtime.h>
#include <hip/hip_bf16.h>

typedef __bf16 bf16;
typedef __attribute__((ext_vector_type(4))) __bf16 bf16x4;
typedef __attribute__((ext_vector_type(8))) __bf16 bf16x8;
typedef __attribute__((ext_vector_type(4))) float f32x4;

// ---------------- async global->LDS helper (16B per lane, wave-uniform LDS base) ----
__device__ __forceinline__ void async_ld16(const void* g, void* l) {
    __builtin_amdgcn_global_load_lds(
        (const __attribute__((address_space(1))) unsigned int*)g,
        (__attribute__((address_space(3))) unsigned int*)l, 16, 0, 0);
}

// ------- fp32 -> bf16 transposed weight convert: in[K][N] -> out[N][K], 2 layers ----
__global__ __launch_bounds__(256) void k_f2bt(const float* __restrict__ in,
                                              bf16* __restrict__ out, int Kd, int Nd) {
    size_t loff = (size_t)blockIdx.y * Kd * Nd;
    int id = blockIdx.x * 256 + threadIdx.x;
    if (id >= Kd * Nd) return;
    int k = id / Nd, n = id - k * Nd;
    out[loff + (size_t)n * Kd + k] = (bf16)in[loff + id];
}

// ------- one-shot attention setup: relIdx table + head-major rpb transpose ---------
__global__ __launch_bounds__(256) void k_aux(const float* __restrict__ rpb,
                                             unsigned short* __restrict__ ridx,
                                             float* __restrict__ rpbT) {
    int e = blockIdx.x * 256 + threadIdx.x;
    if (e < 2401) {
        int i = e / 49, j = e - i * 49;
        int yi = i / 7, xi = i - yi * 7, yj = j / 7, xj = j - yj * 7;
        ridx[e] = (unsigned short)((yi - yj + 6) * 13 + (xi - xj + 6));
    }
    if (e < 4056) {   // 2 layers x 12 heads x 169
        int l = e / 2028, r = e - l * 2028;
        int h = r / 169, p = r - h * 169;
        rpbT[e] = rpb[l * 2028 + p * 12 + h];
    }
}

// ---------------- fused reorder_in + LayerNorm1(l=0): one wave per token -----------
__global__ __launch_bounds__(256) void k_lnr(const float* __restrict__ x,
                                             const float* __restrict__ s,
                                             const float* __restrict__ b,
                                             float* __restrict__ xres,
                                             bf16* __restrict__ h) {
    int traw = blockIdx.x * 4 + (threadIdx.x >> 6);
    int lane = threadIdx.x & 63;
    int bb = traw / 3136;
    int rem = traw - bb * 3136;
    int y = rem / 56, xc = rem - y * 56;
    int w = bb * 64 + (y / 7) * 8 + (xc / 7);
    int n = (y % 7) * 7 + (xc % 7);
    int twin = w * 49 + n;

    const float4* row = (const float4*)(x + (size_t)traw * 384);  // 96 float4
    float4 v0 = row[lane];
    float4 v1 = make_float4(0.f, 0.f, 0.f, 0.f);
    if (lane < 32) v1 = row[64 + lane];
    float sum = v0.x + v0.y + v0.z + v0.w + v1.x + v1.y + v1.z + v1.w;
#pragma unroll
    for (int m = 1; m < 64; m <<= 1) sum += __shfl_xor(sum, m);
    float mu = sum * (1.f / 384.f);
    float sq = (v0.x - mu) * (v0.x - mu) + (v0.y - mu) * (v0.y - mu) +
               (v0.z - mu) * (v0.z - mu) + (v0.w - mu) * (v0.w - mu);
    if (lane < 32)
        sq += (v1.x - mu) * (v1.x - mu) + (v1.y - mu) * (v1.y - mu) +
              (v1.z - mu) * (v1.z - mu) + (v1.w - mu) * (v1.w - mu);
#pragma unroll
    for (int m = 1; m < 64; m <<= 1) sq += __shfl_xor(sq, m);
    float r = rsqrtf(sq * (1.f / 384.f) + 1e-6f);

    float4* xr = (float4*)(xres + (size_t)twin * 384);
    const float4* s4 = (const float4*)s;
    const float4* b4 = (const float4*)b;
    bf16* ho = h + (size_t)twin * 384;
    {
        xr[lane] = v0;
        float4 sv = s4[lane], bv = b4[lane];
        bf16x4 ov;
        ov[0] = (bf16)((v0.x - mu) * r * sv.x + bv.x);
        ov[1] = (bf16)((v0.y - mu) * r * sv.y + bv.y);
        ov[2] = (bf16)((v0.z - mu) * r * sv.z + bv.z);
        ov[3] = (bf16)((v0.w - mu) * r * sv.w + bv.w);
        *(bf16x4*)&ho[lane * 4] = ov;
    }
    if (lane < 32) {
        xr[64 + lane] = v1;
        float4 sv = s4[64 + lane], bv = b4[64 + lane];
        bf16x4 ov;
        ov[0] = (bf16)((v1.x - mu) * r * sv.x + bv.x);
        ov[1] = (bf16)((v1.y - mu) * r * sv.y + bv.y);
        ov[2] = (bf16)((v1.z - mu) * r * sv.z + bv.z);
        ov[3] = (bf16)((v1.w - mu) * r * sv.w + bv.w);
        *(bf16x4*)&ho[256 + lane * 4] = ov;
    }
}

// ---------------- LayerNorm: fp32 residual -> bf16 ---------------------------------
__global__ __launch_bounds__(256) void k_ln(const float* __restrict__ xres,
                                            const float* __restrict__ s,
                                            const float* __restrict__ b,
                                            bf16* __restrict__ h) {
    int t = blockIdx.x * 4 + (threadIdx.x >> 6);
    int lane = threadIdx.x & 63;
    const float4* row = (const float4*)(xres + (size_t)t * 384);
    float4 v0 = row[lane];
    float4 v1 = make_float4(0.f, 0.f, 0.f, 0.f);
    if (lane < 32) v1 = row[64 + lane];
    float sum = v0.x + v0.y + v0.z + v0.w + v1.x + v1.y + v1.z + v1.w;
#pragma unroll
    for (int m = 1; m < 64; m <<= 1) sum += __shfl_xor(sum, m);
    float mu = sum * (1.f / 384.f);
    float sq = (v0.x - mu) * (v0.x - mu) + (v0.y - mu) * (v0.y - mu) +
               (v0.z - mu) * (v0.z - mu) + (v0.w - mu) * (v0.w - mu);
    if (lane < 32)
        sq += (v1.x - mu) * (v1.x - mu) + (v1.y - mu) * (v1.y - mu) +
              (v1.z - mu) * (v1.z - mu) + (v1.w - mu) * (v1.w - mu);
#pragma unroll
    for (int m = 1; m < 64; m <<= 1) sq += __shfl_xor(sq, m);
    float r = rsqrtf(sq * (1.f / 384.f) + 1e-6f);
    const float4* s4 = (const float4*)s;
    const float4* b4 = (const float4*)b;
    bf16* ho = h + (size_t)t * 384;
    {
        float4 sv = s4[lane], bv = b4[lane];
        bf16x4 ov;
        ov[0] = (bf16)((v0.x - mu) * r * sv.x + bv.x);
        ov[1] = (bf16)((v0.y - mu) * r * sv.y + bv.y);
        ov[2] = (bf16)((v0.z - mu) * r * sv.z + bv.z);
        ov[3] = (bf16)((v0.w - mu) * r * sv.w + bv.w);
        *(bf16x4*)&ho[lane * 4] = ov;
    }
    if (lane < 32) {
        float4 sv = s4[64 + lane], bv = b4[64 + lane];
        bf16x4 ov;
        ov[0] = (bf16)((v1.x - mu) * r * sv.x + bv.x);
        ov[1] = (bf16)((v1.y - mu) * r * sv.y + bv.y);
        ov[2] = (bf16)((v1.z - mu) * r * sv.z + bv.z);
        ov[3] = (bf16)((v1.w - mu) * r * sv.w + bv.w);
        *(bf16x4*)&ho[256 + lane * 4] = ov;
    }
}

// ---------------- GELU (tanh approximation, matches jax.nn.gelu) -------------------
__device__ inline float gelu_f(float x) {
    float u = 0.7978845608028654f * (x + 0.044715f * x * x * x);
    float t = 1.f - 2.f / (__expf(2.f * u) + 1.f);
    return 0.5f * x * (1.f + t);
}

// ---------------- GEMM: C[M,N] = A[M,K] @ Bt[N,K]^T (+epilogue) --------------------
// EPI 0: store bf16 | 1: +bias, gelu, store bf16 | 2: resid += | 3: resid += val+bias
// EPI 4: outf[perm(row)] = resid + val + bias (fp32, fused reorder_out)
// 128x128 tile, BK=32, 4 waves (2x2), global_load_lds staging, XOR kseg swizzle.
// THREE LDS buffers (48KB -> 3 blocks/CU), depth-2 pipeline, ONE barrier per K-step.
// XCD-chunked swizzle keeps loads L2-resident so depth-2 slack covers load latency.
// R5-VERIFIED OPTIMUM for this template (1060 us total). Three structural rewrites
// (rolling 2-tile R4, 256x128 wave-tile R6, B-direct-from-L2 R7) all regressed:
// constraints are >=3 blocks/CU TLP, LDS-traffic invariance, and compiler vmcnt
// drains under register prefetch. Do not re-attempt those within this template.
template <int EPI>
__global__ __launch_bounds__(256) void k_gemm(const bf16* __restrict__ A,
                                              const bf16* __restrict__ Bt,
                                              const float* __restrict__ bias,
                                              float* __restrict__ resid,
                                              bf16* __restrict__ Cout,
                                              float* __restrict__ outf,
                                              int N, int K) {
    __shared__ __align__(16) char lds[49152];   // 3 x (A 8KB + B 8KB)
    int tid = threadIdx.x;

    int nwg = gridDim.x * gridDim.y;
    int orig = blockIdx.y * gridDim.x + blockIdx.x;
    int q = nwg >> 3, r8 = nwg & 7;
    int xcd = orig & 7, idx = orig >> 3;
    int wg = (xcd < r8 ? xcd * (q + 1) : r8 * (q + 1) + (xcd - r8) * q) + idx;
    int n0 = (wg % gridDim.x) * 128;
    int m0 = (wg / gridDim.x) * 128;

    int wave = tid >> 6, lane = tid & 63;
    int wm = (wave >> 1) * 64, wn = (wave & 1) * 64;
    int col = lane & 15, quad = lane >> 4;

    f32x4 acc[4][4] = {};

    int r0 = 2 * wave * 16 + (lane >> 2);
    int ksl = (lane & 3) ^ ((r0 >> 1) & 3);
    const bf16* ga0 = A + (size_t)(m0 + r0) * K + ksl * 8;
    const bf16* gb0 = Bt + (size_t)(n0 + r0) * K + ksl * 8;
    size_t rowK16 = (size_t)16 * K;
    int ldsoff = 2 * wave * 512;

    int NT = K >> 5;

    auto stage = [&](int t, int b) {
        const bf16* a = ga0 + t * 32;
        const bf16* g = gb0 + t * 32;
        char* base = (char*)lds + b * 16384;
        bf16* Ab = (bf16*)base;
        bf16* Bb = (bf16*)(base + 8192);
        async_ld16(a, Ab + ldsoff);
        async_ld16(a + rowK16, Ab + ldsoff + 512);
        async_ld16(g, Bb + ldsoff);
        async_ld16(g + rowK16, Bb + ldsoff + 512);
    };

    stage(0, 0);
    stage(1, 1);

    int buf = 0;   // t % 3
    for (int t = 0; t < NT; ++t) {
        if (t < NT - 1)
            asm volatile("s_waitcnt vmcnt(4) lgkmcnt(0)\n\ts_barrier" ::: "memory");
        else
            asm volatile("s_waitcnt vmcnt(0) lgkmcnt(0)\n\ts_barrier" ::: "memory");

        if (t + 2 < NT) {
            int sb = buf + 2; if (sb >= 3) sb -= 3;
            stage(t + 2, sb);
        }

        const char* base = (const char*)lds + buf * 16384;
        const bf16* Ab = (const bf16*)base;
        const bf16* Bb = (const bf16*)(base + 8192);
        bf16x8 af[4], bfv[4];
#pragma unroll
        for (int i = 0; i < 4; i++) {
            int ra = wm + i * 16 + col;
            af[i] = *(const bf16x8*)&Ab[ra * 32 + ((quad ^ ((ra >> 1) & 3)) << 3)];
            int rb = wn + i * 16 + col;
            bfv[i] = *(const bf16x8*)&Bb[rb * 32 + ((quad ^ ((rb >> 1) & 3)) << 3)];
        }
#pragma unroll
        for (int mi = 0; mi < 4; mi++)
#pragma unroll
            for (int ni = 0; ni < 4; ni++)
                acc[mi][ni] = __builtin_amdgcn_mfma_f32_16x16x32_bf16(
                    af[mi], bfv[ni], acc[mi][ni], 0, 0, 0);
        buf = (buf == 2) ? 0 : buf + 1;
    }

    __syncthreads();
    float* scrw = (float*)lds + wave * (16 * 68);

    int prow = lane >> 3;
    int pc0 = (lane & 7) * 8;
#pragma unroll
    for (int mi = 0; mi < 4; mi++) {
#pragma unroll
        for (int ni = 0; ni < 4; ni++)
#pragma unroll
            for (int r = 0; r < 4; r++)
                scrw[(quad * 4 + r) * 68 + ni * 16 + col] = acc[mi][ni][r];
#pragma unroll
        for (int h = 0; h < 2; h++) {
            int lr = h * 8 + prow;
            const float* sp = scrw + lr * 68 + pc0;
            float4 u0 = *(const float4*)sp;
            float4 u1 = *(const float4*)(sp + 4);
            int gm = m0 + wm + mi * 16 + lr;
            int gn = n0 + wn + pc0;
            size_t off = (size_t)gm * N + gn;
            if (EPI == 0) {
                bf16x8 ov;
                ov[0] = (bf16)u0.x; ov[1] = (bf16)u0.y; ov[2] = (bf16)u0.z; ov[3] = (bf16)u0.w;
                ov[4] = (bf16)u1.x; ov[5] = (bf16)u1.y; ov[6] = (bf16)u1.z; ov[7] = (bf16)u1.w;
                *(bf16x8*)&Cout[off] = ov;
            } else if (EPI == 1) {
                float4 b0 = *(const float4*)&bias[gn];
                float4 b1 = *(const float4*)&bias[gn + 4];
                bf16x8 ov;
                ov[0] = (bf16)gelu_f(u0.x + b0.x); ov[1] = (bf16)gelu_f(u0.y + b0.y);
                ov[2] = (bf16)gelu_f(u0.z + b0.z); ov[3] = (bf16)gelu_f(u0.w + b0.w);
                ov[4] = (bf16)gelu_f(u1.x + b1.x); ov[5] = (bf16)gelu_f(u1.y + b1.y);
                ov[6] = (bf16)gelu_f(u1.z + b1.z); ov[7] = (bf16)gelu_f(u1.w + b1.w);
                *(bf16x8*)&Cout[off] = ov;
            } else if (EPI == 2) {
                float4 r0v = *(const float4*)&resid[off];
                float4 r1v = *(const float4*)&resid[off + 4];
                r0v.x += u0.x; r0v.y += u0.y; r0v.z += u0.z; r0v.w += u0.w;
                r1v.x += u1.x; r1v.y += u1.y; r1v.z += u1.z; r1v.w += u1.w;
                *(float4*)&resid[off] = r0v;
                *(float4*)&resid[off + 4] = r1v;
            } else if (EPI == 3) {
                float4 b0 = *(const float4*)&bias[gn];
                float4 b1 = *(const float4*)&bias[gn + 4];
                float4 r0v = *(const float4*)&resid[off];
                float4 r1v = *(const float4*)&resid[off + 4];
                r0v.x += u0.x + b0.x; r0v.y += u0.y + b0.y;
                r0v.z += u0.z + b0.z; r0v.w += u0.w + b0.w;
                r1v.x += u1.x + b1.x; r1v.y += u1.y + b1.y;
                r1v.z += u1.z + b1.z; r1v.w += u1.w + b1.w;
                *(float4*)&resid[off] = r0v;
                *(float4*)&resid[off + 4] = r1v;
            } else {
                // EPI 4: fp32 out at permuted raw row (fused reorder_out)
                float4 b0 = *(const float4*)&bias[gn];
                float4 b1 = *(const float4*)&bias[gn + 4];
                float4 r0v = *(const float4*)&resid[off];
                float4 r1v = *(const float4*)&resid[off + 4];
                r0v.x += u0.x + b0.x; r0v.y += u0.y + b0.y;
                r0v.z += u0.z + b0.z; r0v.w += u0.w + b0.w;
                r1v.x += u1.x + b1.x; r1v.y += u1.y + b1.y;
                r1v.z += u1.z + b1.z; r1v.w += u1.w + b1.w;
                int wdx = gm / 49, n = gm - wdx * 49;
                int bb = wdx >> 6, r64 = wdx & 63;
                int n7 = n / 7;
                int yy = (r64 >> 3) * 7 + n7;
                int xx = (r64 & 7) * 7 + (n - n7 * 7);
                size_t traw = ((size_t)((bb * 56 + yy) * 56 + xx)) * 384 + gn;
                *(float4*)&outf[traw] = r0v;
                *(float4*)&outf[traw + 4] = r1v;
            }
        }
    }
}

// ---------------- MFMA window attention: one WAVE per (window, head) ---------------
// T5: s_setprio(1) around the MFMA clusters — waves in this block alternate between
// long serial softmax VALU phases and MFMA phases (role diversity), the regime where
// setprio pays on attn (m191: +4-7%); no-op worst case.
__global__ __launch_bounds__(256) void k_attn(const bf16* __restrict__ qkv,
                                              const unsigned short* __restrict__ ridx,
                                              const float* __restrict__ rpbT,
                                              bf16* __restrict__ o) {
    __shared__ unsigned short relIdx[2401];
    __shared__ float rpbs[4][169];
    __shared__ __align__(16) bf16 Vs[4][32 * 72];
    __shared__ __align__(16) bf16 Ps[4][64 * 72];

    int tid = threadIdx.x;
    int wave = tid >> 6, lane = tid & 63;
    int col = lane & 15, quad = lane >> 4;
    int w = blockIdx.x;
    int head = blockIdx.y * 4 + wave;
    const float scale = 0.17677669529663687f;

    for (int e = tid; e < 2401; e += 256) relIdx[e] = ridx[e];
    for (int e = lane; e < 169; e += 64) rpbs[wave][e] = rpbT[head * 169 + e];

    const bf16* base = qkv + (size_t)w * 49 * 1152 + head * 32;
    bf16* vsw = Vs[wave];
    bf16* psw = Ps[wave];

    bf16x4 z4 = {(bf16)0.f, (bf16)0.f, (bf16)0.f, (bf16)0.f};
    for (int e = lane; e < 576; e += 64) *(bf16x4*)&vsw[e * 4] = z4;
    for (int e = lane; e < 392; e += 64) {
        int j = e >> 3, d4 = (e & 7) * 4;
        bf16x4 vv = *(const bf16x4*)&base[768 + (size_t)j * 1152 + d4];
        vsw[(d4 + 0) * 72 + j] = vv[0];
        vsw[(d4 + 1) * 72 + j] = vv[1];
        vsw[(d4 + 2) * 72 + j] = vv[2];
        vsw[(d4 + 3) * 72 + j] = vv[3];
    }

    __syncthreads();

    bf16x8 qf[4], kf[4];
#pragma unroll
    for (int mi = 0; mi < 4; mi++) {
        size_t row = (size_t)(mi * 16 + col) * 1152 + quad * 8;
        qf[mi] = *(const bf16x8*)&base[row];
        kf[mi] = *(const bf16x8*)&base[384 + row];
    }

    f32x4 S[4][4] = {};
    __builtin_amdgcn_s_setprio(1);
#pragma unroll
    for (int mi = 0; mi < 4; mi++)
#pragma unroll
        for (int nj = 0; nj < 4; nj++)
            S[mi][nj] = __builtin_amdgcn_mfma_f32_16x16x32_bf16(qf[mi], kf[nj], S[mi][nj], 0, 0, 0);
    __builtin_amdgcn_s_setprio(0);

    float* rp = rpbs[wave];
#pragma unroll
    for (int mi = 0; mi < 4; mi++) {
#pragma unroll
        for (int r = 0; r < 4; r++) {
            int ii = mi * 16 + quad * 4 + r;
            int ir = (ii < 49 ? ii : 0) * 49;
            float sv[4];
            float mx = -1e30f;
#pragma unroll
            for (int nj = 0; nj < 4; nj++) {
                int j = nj * 16 + col;
                float v;
                if (j < 49) v = S[mi][nj][r] * scale + rp[relIdx[ir + j]];
                else v = -1e30f;
                sv[nj] = v;
                mx = fmaxf(mx, v);
            }
#pragma unroll
            for (int m = 1; m < 16; m <<= 1) mx = fmaxf(mx, __shfl_xor(mx, m));
            float sum = 0.f;
#pragma unroll
            for (int nj = 0; nj < 4; nj++) {
                float p = __expf(sv[nj] - mx);
                sv[nj] = p;
                sum += p;
            }
#pragma unroll
            for (int m = 1; m < 16; m <<= 1) sum += __shfl_xor(sum, m);
            float is = 1.f / sum;
#pragma unroll
            for (int nj = 0; nj < 4; nj++)
                psw[ii * 72 + nj * 16 + col] = (bf16)(sv[nj] * is);
        }
    }

    __syncthreads();

    f32x4 O[4][2] = {};
    __builtin_amdgcn_s_setprio(1);
#pragma unroll
    for (int kt = 0; kt < 2; kt++) {
        bf16x8 vb[2];
#pragma unroll
        for (int nt = 0; nt < 2; nt++)
            vb[nt] = *(const bf16x8*)&vsw[(nt * 16 + col) * 72 + kt * 32 + quad * 8];
#pragma unroll
        for (int mi = 0; mi < 4; mi++) {
            bf16x8 pa = *(const bf16x8*)&psw[(mi * 16 + col) * 72 + kt * 32 + quad * 8];
#pragma unroll
            for (int nt = 0; nt < 2; nt++)
                O[mi][nt] = __builtin_amdgcn_mfma_f32_16x16x32_bf16(pa, vb[nt], O[mi][nt], 0, 0, 0);
        }
    }
    __builtin_amdgcn_s_setprio(0);

    bf16* ob = o + (size_t)w * 49 * 384 + head * 32;
#pragma unroll
    for (int mi = 0; mi < 4; mi++) {
#pragma unroll
        for (int r = 0; r < 4; r++) {
            int i = mi * 16 + quad * 4 + r;
            if (i < 49) {
#pragma unroll
                for (int nt = 0; nt < 2; nt++)
                    ob[(size_t)i * 384 + nt * 16 + col] = (bf16)O[mi][nt][r];
            }
        }
    }
}

// ---------------- launch ----------------
extern "C" void kernel_launch(void* const* d_in, const int* in_sizes, int n_in,
                              void* d_out, int out_size, void* d_ws, size_t ws_size,
                              hipStream_t stream) {
    const float* x      = (const float*)d_in[0];
    const float* ln1_s  = (const float*)d_in[1];
    const float* ln1_b  = (const float*)d_in[2];
    const float* qkv_w  = (const float*)d_in[3];
    const float* rpb    = (const float*)d_in[4];
    const float* proj_w = (const float*)d_in[5];
    const float* ln2_s  = (const float*)d_in[6];
    const float* ln2_b  = (const float*)d_in[7];
    const float* mlp_w1 = (const float*)d_in[8];
    const float* mlp_b1 = (const float*)d_in[9];
    const float* mlp_w2 = (const float*)d_in[10];
    const float* mlp_b2 = (const float*)d_in[11];
    float* out = (float*)d_out;

    char* ws = (char*)d_ws;
    float* xres  = (float*)ws;                     // 77,070,336 B
    bf16* qkvbuf = (bf16*)(ws + 77070336);         // 115,605,504 B
    bf16* obuf   = (bf16*)(ws + 192675840);        // 38,535,168 B
    bf16* wbuf   = (bf16*)(ws + 231211008);        // 7,077,888 B
    bf16* hidden = qkvbuf;                         // aliases qkv+obuf (154,140,672 B)
    bf16* hbuf   = (bf16*)d_out;                   // 38.5 MB scratch inside 77 MB out

    unsigned short* ridx = (unsigned short*)((char*)d_out + 40000000);   // 4,802 B
    float* rpbT          = (float*)((char*)d_out + 40016384);            // 16,224 B

    bf16* qkvw_b  = wbuf;                 // 884,736 elems (2 layers, transposed [N][K])
    bf16* projw_b = wbuf + 884736;        // 294,912
    bf16* mlp1_b  = wbuf + 1179648;       // 1,179,648
    bf16* mlp2_b  = wbuf + 2359296;       // 1,179,648

    k_f2bt<<<dim3(1728, 2), 256, 0, stream>>>(qkv_w, qkvw_b, 384, 1152);
    k_f2bt<<<dim3(576, 2), 256, 0, stream>>>(proj_w, projw_b, 384, 384);
    k_f2bt<<<dim3(2304, 2), 256, 0, stream>>>(mlp_w1, mlp1_b, 384, 1536);
    k_f2bt<<<dim3(2304, 2), 256, 0, stream>>>(mlp_w2, mlp2_b, 1536, 384);
    k_aux<<<16, 256, 0, stream>>>(rpb, ridx, rpbT);

    // fused reorder_in + LN1(l=0)
    k_lnr<<<12544, 256, 0, stream>>>(x, ln1_s, ln1_b, xres, hbuf);

    for (int l = 0; l < 2; l++) {
        k_gemm<0><<<dim3(9, 392), 256, 0, stream>>>(
            hbuf, qkvw_b + (size_t)l * 442368, nullptr, nullptr, qkvbuf, nullptr, 1152, 384);
        k_attn<<<dim3(1024, 3), 256, 0, stream>>>(qkvbuf, ridx, rpbT + l * 2028, obuf);
        k_gemm<2><<<dim3(3, 392), 256, 0, stream>>>(
            obuf, projw_b + (size_t)l * 147456, nullptr, xres, nullptr, nullptr, 384, 384);
        k_ln<<<12544, 256, 0, stream>>>(xres, ln2_s + l * 384, ln2_b + l * 384, hbuf);
        k_gemm<1><<<dim3(12, 392), 256, 0, stream>>>(
            hbuf, mlp1_b + (size_t)l * 589824, mlp_b1 + l * 1536, nullptr, hidden, nullptr, 1536, 384);
        if (l == 0) {
            k_gemm<3><<<dim3(3, 392), 256, 0, stream>>>(
                hidden, mlp2_b, mlp_b2, xres, nullptr, nullptr, 384, 1536);
            k_ln<<<12544, 256, 0, stream>>>(xres, ln1_s + 384, ln1_b + 384, hbuf);
        } else {
            k_gemm<4><<<dim3(3, 392), 256, 0, stream>>>(
                hidden, mlp2_b + 589824, mlp_b2 + 384, xres, nullptr, out, 384, 1536);
        }
    }
}